// Round 3
// baseline (1712.755 us; speedup 1.0000x reference)
//
#include <hip/hip_runtime.h>
#include <hip/hip_fp16.h>

// ============================================================================
// WindowAttention (Swin-V2 style) fused kernel for MI355X (gfx950).
// BW=4096 windows, N=64 tokens, DIM=256, HEADS=8, HDIM=32, fp32 in/out.
//
// Design (round 3 = round 2 + double-buffered per-head LDS; no HW data yet —
// three consecutive GPU acquisition timeouts):
//   kprep: fp32->fp16 weight conversion + CPB MLP table (225 x 8, with
//          16*sigmoid pre-applied).
//   kmain: one block per window (256 thr = 4 waves).
//     phase0: x -> LDS fp16; hoist per-wave x A-fragments to registers
//     per head: QKV tile-GEMM (B-frags from global/L2), RMSNorm (fp32,
//               shfl butterfly), QK^T (16x16x32 f16 MFMA), softmax fp32
//               (1/sum deferred to PV accumulators), P/V^T LDS transpose,
//               PV MFMA.  qs/ks/vts double-buffered on h&1 -> ONE barrier
//               per head (WAR on buffer c is fenced by the barrier of the
//               previous iteration on the other buffer).
//     phase4: y -> LDS fp16 (reuse xs), proj GEMM (wave-split output cols
//             so proj_w is read once per block), +bias, fp32 store.
// All MFMA A/B fragments use the same per-lane k mapping (k = hi*8+j within
// each 32-chunk) so results are invariant to the HW intra-lane k order.
// C/D layout: col = lane&15, row = (lane>>4)*4 + reg  [m89-verified].
// LDS: 33792 + 2*(5120+5120+4608) + 9216 = 72704 B -> 2 blocks/CU.
// ============================================================================

#define NTOK 64
#define DIMC 256
#define NHEAD 8
#define HD 32
#define NWIN 4096
#define RMS_EPS 1.1920928955078125e-07f  // np.finfo(np.float32).eps
#define LOG2E 1.4426950408889634f

typedef _Float16 f16;
typedef __attribute__((ext_vector_type(8))) _Float16 f16x8;
typedef __attribute__((ext_vector_type(4))) _Float16 f16x4;
typedef __attribute__((ext_vector_type(4))) float f32x4;

// ws layout (bytes); requires ws_size >= 531488
#define OFF_QKVW 0                        // 768*256 f16 = 393216
#define OFF_PROJW 393216                  // 256*256 f16 = 131072
#define OFF_TABLE (393216 + 131072)       // 225*8 f32  = 7200

// ---------------------------------------------------------------------------
// Prep: weight fp16 conversion + continuous-position-bias table.
// grid 256 x 256. Blocks 0..224 additionally run the CPB MLP for their
// relative-position index; table stores 16*sigmoid(mlp_out) directly.
// ---------------------------------------------------------------------------
__global__ __launch_bounds__(256) void kprep(
    const float* __restrict__ qkv_w, const float* __restrict__ cpb_w1,
    const float* __restrict__ cpb_b1, const float* __restrict__ cpb_w2,
    const float* __restrict__ proj_w, f16* __restrict__ qkv_w16,
    f16* __restrict__ proj_w16, float* __restrict__ tableS) {
  const int tid = threadIdx.x;
  const int bid = blockIdx.x;
  const int gtid = bid * 256 + tid;

  // weight conversion (grid-stride)
  for (int i = gtid; i < 768 * 256; i += 256 * 256) qkv_w16[i] = (f16)qkv_w[i];
  for (int i = gtid; i < 256 * 256; i += 256 * 256) proj_w16[i] = (f16)proj_w[i];

  if (bid < 225) {
    // relative coords for this table row: idx = (dy+7)*15 + (dx+7)
    const int a = bid / 15, b2 = bid % 15;
    const float dy = (float)(a - 7), dx = (float)(b2 - 7);
    const float gy = dy * (8.0f / 7.0f), gx = dx * (8.0f / 7.0f);
    const float sy = (gy > 0.f) ? 1.f : ((gy < 0.f) ? -1.f : 0.f);
    const float sx = (gx > 0.f) ? 1.f : ((gx < 0.f) ? -1.f : 0.f);
    const float c0 = sy * log2f(fabsf(gy) + 1.0f) * (1.0f / 3.0f);  // /log2(8)
    const float c1 = sx * log2f(fabsf(gx) + 1.0f) * (1.0f / 3.0f);
    // third channel is zero-padded -> contributes nothing.

    __shared__ float hid[512];
    for (int j = tid; j < 512; j += 256) {
      float h = c0 * cpb_w1[3 * j] + c1 * cpb_w1[3 * j + 1] + cpb_b1[j];
      hid[j] = fmaxf(h, 0.0f);
    }
    __syncthreads();
    __shared__ float part[8][256];
#pragma unroll
    for (int h = 0; h < 8; ++h)
      part[h][tid] = hid[tid] * cpb_w2[h * 512 + tid] +
                     hid[tid + 256] * cpb_w2[h * 512 + tid + 256];
    __syncthreads();
    for (int s = 128; s > 0; s >>= 1) {
      if (tid < s) {
#pragma unroll
        for (int h = 0; h < 8; ++h) part[h][tid] += part[h][tid + s];
      }
      __syncthreads();
    }
    if (tid < 8) {
      float v = part[tid][0];
      tableS[bid * 8 + tid] = 16.0f / (1.0f + expf(-v));  // 16*sigmoid
    }
  }
}

// ---------------------------------------------------------------------------
// Main fused kernel: one window per block.
// ---------------------------------------------------------------------------
__global__ __launch_bounds__(256, 2) void kmain(
    const float* __restrict__ x, const f16* __restrict__ qkv_w16,
    const float* __restrict__ qkv_b, const float* __restrict__ tableS,
    const float* __restrict__ nqw, const float* __restrict__ nkw,
    const f16* __restrict__ proj_w16, const float* __restrict__ proj_b,
    float* __restrict__ out) {
  alignas(16) __shared__ f16 xs[64][264];       // x fp16 (later reused for y)
  alignas(16) __shared__ f16 qs[2][64][40];     // normalized q  [tok][dim]
  alignas(16) __shared__ f16 ks[2][64][40];     // normalized k  [tok][dim]
  alignas(16) __shared__ f16 vts[2][32][72];    // v transposed  [dim][tok]
  alignas(16) __shared__ f16 ps[4][16][72];     // per-wave P    [row][key]

  const int tid = threadIdx.x;
  const int wv = tid >> 6;       // wave 0..3 (owns token rows 16*wv..+16)
  const int lane = tid & 63;
  const int hi = lane >> 4;      // 0..3
  const int lo = lane & 15;      // 0..15
  const int b = blockIdx.x;

  const float* xb = x + (size_t)b * (NTOK * DIMC);

  // ---- phase 0: stage x as fp16 into LDS ----
  for (int i = tid; i < 64 * 64; i += 256) {
    const int r = i >> 6, c4 = (i & 63) * 4;
    const float4 v = *reinterpret_cast<const float4*>(xb + r * 256 + c4);
    f16x4 hv = {(f16)v.x, (f16)v.y, (f16)v.z, (f16)v.w};
    *reinterpret_cast<f16x4*>(&xs[r][c4]) = hv;
  }

  // Precompute relative-position table offsets (x8 for head stride) for the
  // 16 (row,key) pairs this lane sees in the score tiles.
  int ridx[4][4];  // [ct][reg]
#pragma unroll
  for (int reg = 0; reg < 4; ++reg) {
    const int row = 16 * wv + hi * 4 + reg;
    const int ry = row >> 3, rx = row & 7;
#pragma unroll
    for (int ct = 0; ct < 4; ++ct) {
      const int key = 16 * ct + lo;
      const int ky = key >> 3, kx = key & 7;
      ridx[ct][reg] = ((ry - ky + 7) * 15 + (rx - kx + 7)) * 8;
    }
  }
  // RMSNorm weights (shared across heads; dim = ct*16+lo)
  const float wq0 = nqw[lo], wq1 = nqw[16 + lo];
  const float wk0 = nkw[lo], wk1 = nkw[16 + lo];

  f32x4 yacc[16];  // y accumulator: tile t -> channels [16t,16t+16), rows own
#pragma unroll
  for (int t = 0; t < 16; ++t) yacc[t] = (f32x4){0.f, 0.f, 0.f, 0.f};

  __syncthreads();

  const int arow = 16 * wv + lo;  // A-fragment row (token) for this lane

  // Hoist the head-invariant x A-fragments into registers (32 VGPRs).
  f16x8 af_x[8];
#pragma unroll
  for (int kk = 0; kk < 8; ++kk)
    af_x[kk] = *reinterpret_cast<const f16x8*>(&xs[arow][kk * 32 + hi * 8]);

  for (int h = 0; h < NHEAD; ++h) {
    const int cb = h & 1;  // double-buffer index for qs/ks/vts
    // ---- phase 1: QKV tile GEMM for head h ----
    f32x4 acc[3][2];
#pragma unroll
    for (int s = 0; s < 3; ++s)
#pragma unroll
      for (int ct = 0; ct < 2; ++ct) acc[s][ct] = (f32x4){0.f, 0.f, 0.f, 0.f};

#pragma unroll
    for (int kk = 0; kk < 8; ++kk) {
#pragma unroll
      for (int s = 0; s < 3; ++s) {
#pragma unroll
        for (int ct = 0; ct < 2; ++ct) {
          const int ch = s * 256 + h * 32 + ct * 16 + lo;
          const f16x8 bfrag = *reinterpret_cast<const f16x8*>(
              qkv_w16 + ch * 256 + kk * 32 + hi * 8);
          acc[s][ct] = __builtin_amdgcn_mfma_f32_16x16x32_f16(
              af_x[kk], bfrag, acc[s][ct], 0, 0, 0);
        }
      }
    }
    // + qkv bias (per channel = per D-column)
#pragma unroll
    for (int s = 0; s < 3; ++s)
#pragma unroll
      for (int ct = 0; ct < 2; ++ct) {
        const float bias = qkv_b[s * 256 + h * 32 + ct * 16 + lo];
#pragma unroll
        for (int reg = 0; reg < 4; ++reg) acc[s][ct][reg] += bias;
      }

    // ---- phase 1b: RMSNorm q,k -> LDS ; V^T -> LDS ----
    {
      float ss[4], tt[4];
#pragma unroll
      for (int reg = 0; reg < 4; ++reg) {
        ss[reg] = acc[0][0][reg] * acc[0][0][reg] +
                  acc[0][1][reg] * acc[0][1][reg];
        tt[reg] = acc[1][0][reg] * acc[1][0][reg] +
                  acc[1][1][reg] * acc[1][1][reg];
      }
#pragma unroll
      for (int m = 1; m < 16; m <<= 1) {
#pragma unroll
        for (int reg = 0; reg < 4; ++reg) {
          ss[reg] += __shfl_xor(ss[reg], m);
          tt[reg] += __shfl_xor(tt[reg], m);
        }
      }
#pragma unroll
      for (int reg = 0; reg < 4; ++reg) {
        const int row = 16 * wv + hi * 4 + reg;
        const float rq = 1.0f / sqrtf(ss[reg] * (1.0f / 32.0f) + RMS_EPS);
        const float rk = 1.0f / sqrtf(tt[reg] * (1.0f / 32.0f) + RMS_EPS);
        qs[cb][row][lo] = (f16)(acc[0][0][reg] * rq * wq0);
        qs[cb][row][16 + lo] = (f16)(acc[0][1][reg] * rq * wq1);
        ks[cb][row][lo] = (f16)(acc[1][0][reg] * rk * wk0);
        ks[cb][row][16 + lo] = (f16)(acc[1][1][reg] * rk * wk1);
      }
      // V transposed: vts[dim][token]; 4 consecutive tokens per lane -> b64
#pragma unroll
      for (int ct = 0; ct < 2; ++ct) {
        f16x4 pv = {(f16)acc[2][ct][0], (f16)acc[2][ct][1],
                    (f16)acc[2][ct][2], (f16)acc[2][ct][3]};
        *reinterpret_cast<f16x4*>(&vts[cb][ct * 16 + lo][16 * wv + hi * 4]) =
            pv;
      }
    }
    __syncthreads();  // publish qs/ks/vts[cb]; also fences WAR for buffer cb
                      // of iteration h+2 (its writers must pass THIS barrier's
                      // successor on the other buffer first).

    // ---- phase 2: scores + softmax (fp32, deferred 1/sum) ----
    const f16x8 aq = *reinterpret_cast<const f16x8*>(&qs[cb][arow][hi * 8]);
    float logit[4][4];
#pragma unroll
    for (int ct = 0; ct < 4; ++ct) {
      const f16x8 bk =
          *reinterpret_cast<const f16x8*>(&ks[cb][16 * ct + lo][hi * 8]);
      f32x4 z = {0.f, 0.f, 0.f, 0.f};
      z = __builtin_amdgcn_mfma_f32_16x16x32_f16(aq, bk, z, 0, 0, 0);
#pragma unroll
      for (int reg = 0; reg < 4; ++reg)
        logit[ct][reg] = z[reg] + tableS[ridx[ct][reg] + h];
    }
    float mx[4], sum[4];
#pragma unroll
    for (int reg = 0; reg < 4; ++reg) {
      mx[reg] = fmaxf(fmaxf(logit[0][reg], logit[1][reg]),
                      fmaxf(logit[2][reg], logit[3][reg]));
    }
#pragma unroll
    for (int m = 1; m < 16; m <<= 1)
#pragma unroll
      for (int reg = 0; reg < 4; ++reg)
        mx[reg] = fmaxf(mx[reg], __shfl_xor(mx[reg], m));
#pragma unroll
    for (int reg = 0; reg < 4; ++reg) sum[reg] = 0.f;
#pragma unroll
    for (int ct = 0; ct < 4; ++ct)
#pragma unroll
      for (int reg = 0; reg < 4; ++reg) {
        const float p = exp2f((logit[ct][reg] - mx[reg]) * LOG2E);
        logit[ct][reg] = p;
        sum[reg] += p;
      }
#pragma unroll
    for (int m = 1; m < 16; m <<= 1)
#pragma unroll
      for (int reg = 0; reg < 4; ++reg) sum[reg] += __shfl_xor(sum[reg], m);
    // store unnormalized P (<=1) as fp16 in A-fragment layout (per-wave buf)
#pragma unroll
    for (int ct = 0; ct < 4; ++ct)
#pragma unroll
      for (int reg = 0; reg < 4; ++reg)
        ps[wv][hi * 4 + reg][ct * 16 + lo] = (f16)logit[ct][reg];
    float inv[4];
#pragma unroll
    for (int reg = 0; reg < 4; ++reg) inv[reg] = 1.0f / sum[reg];

    // ---- phase 3: PV (ps is per-wave: no cross-wave sync needed) ----
#pragma unroll
    for (int kc = 0; kc < 2; ++kc) {
      const f16x8 ap =
          *reinterpret_cast<const f16x8*>(&ps[wv][lo][kc * 32 + hi * 8]);
#pragma unroll
      for (int ct = 0; ct < 2; ++ct) {
        const f16x8 bv = *reinterpret_cast<const f16x8*>(
            &vts[cb][ct * 16 + lo][kc * 32 + hi * 8]);
        yacc[2 * h + ct] = __builtin_amdgcn_mfma_f32_16x16x32_f16(
            ap, bv, yacc[2 * h + ct], 0, 0, 0);
      }
    }
#pragma unroll
    for (int ct = 0; ct < 2; ++ct)
#pragma unroll
      for (int reg = 0; reg < 4; ++reg) yacc[2 * h + ct][reg] *= inv[reg];
    // no end-of-loop barrier: next head writes the OTHER buffer.
  }

  // ---- phase 4: y -> LDS (reuse xs; each wave writes only its own rows) ----
#pragma unroll
  for (int t = 0; t < 16; ++t)
#pragma unroll
    for (int reg = 0; reg < 4; ++reg)
      xs[16 * wv + hi * 4 + reg][t * 16 + lo] = (f16)yacc[t][reg];
  __syncthreads();

#pragma unroll
  for (int t = 0; t < 16; ++t) yacc[t] = (f32x4){0.f, 0.f, 0.f, 0.f};

  // wave wv computes output columns [64*wv, 64*wv+64) for ALL 64 tokens
#pragma unroll
  for (int kk = 0; kk < 8; ++kk) {
    f16x8 af[4];
#pragma unroll
    for (int rt = 0; rt < 4; ++rt)
      af[rt] =
          *reinterpret_cast<const f16x8*>(&xs[rt * 16 + lo][kk * 32 + hi * 8]);
#pragma unroll
    for (int ct = 0; ct < 4; ++ct) {
      const int oc = 64 * wv + ct * 16 + lo;
      const f16x8 bf = *reinterpret_cast<const f16x8*>(proj_w16 + oc * 256 +
                                                       kk * 32 + hi * 8);
#pragma unroll
      for (int rt = 0; rt < 4; ++rt)
        yacc[rt * 4 + ct] = __builtin_amdgcn_mfma_f32_16x16x32_f16(
            af[rt], bf, yacc[rt * 4 + ct], 0, 0, 0);
    }
  }

  float* ob = out + (size_t)b * (NTOK * DIMC);
#pragma unroll
  for (int ct = 0; ct < 4; ++ct) {
    const int oc = 64 * wv + ct * 16 + lo;
    const float pb = proj_b[oc];
#pragma unroll
    for (int rt = 0; rt < 4; ++rt)
#pragma unroll
      for (int reg = 0; reg < 4; ++reg) {
        const int tok = rt * 16 + hi * 4 + reg;
        ob[tok * 256 + oc] = yacc[rt * 4 + ct][reg] + pb;
      }
  }
}

// ---------------------------------------------------------------------------
extern "C" void kernel_launch(void* const* d_in, const int* in_sizes, int n_in,
                              void* d_out, int out_size, void* d_ws,
                              size_t ws_size, hipStream_t stream) {
  const float* x = (const float*)d_in[0];
  const float* qkv_w = (const float*)d_in[1];
  const float* qkv_b = (const float*)d_in[2];
  const float* cpb_w1 = (const float*)d_in[3];
  const float* cpb_b1 = (const float*)d_in[4];
  const float* cpb_w2 = (const float*)d_in[5];
  const float* nqw = (const float*)d_in[6];
  const float* nkw = (const float*)d_in[7];
  const float* proj_w = (const float*)d_in[8];
  const float* proj_b = (const float*)d_in[9];
  float* out = (float*)d_out;

  char* wsb = (char*)d_ws;
  f16* qkv_w16 = (f16*)(wsb + OFF_QKVW);
  f16* proj_w16 = (f16*)(wsb + OFF_PROJW);
  float* tableS = (float*)(wsb + OFF_TABLE);

  kprep<<<256, 256, 0, stream>>>(qkv_w, cpb_w1, cpb_b1, cpb_w2, proj_w,
                                 qkv_w16, proj_w16, tableS);
  kmain<<<NWIN, 256, 0, stream>>>(x, qkv_w16, qkv_b, tableS, nqw, nkw,
                                  proj_w16, proj_b, out);
}